// Round 1
// baseline (228.660 us; speedup 1.0000x reference)
//
#include <hip/hip_runtime.h>

#define FD 128

// edge_index may arrive as int32 or int64; uniform-branch on a device-detected flag.
__device__ __forceinline__ long long edge_at(const void* ei, int is32, long long idx) {
    return is32 ? (long long)((const int*)ei)[idx] : ((const long long*)ei)[idx];
}

// Sample odd 32-bit words of edge_index. Values are < 2^17, so if the buffer is
// int64, every odd word (high half) is 0. Any nonzero odd word => int32.
__global__ void detect_kernel(const unsigned int* __restrict__ words,
                              unsigned int* __restrict__ flag_or) {
    unsigned int acc = 0;
    for (int i = threadIdx.x; i < 2048; i += blockDim.x)
        acc |= words[2 * i + 1];
    if (acc) atomicOr(flag_or, 1u);
}

// deg_cnt[v] = number of edges with dst == v  (self-loop +1 applied at read time)
__global__ void deg_kernel(const void* __restrict__ ei, const unsigned int* __restrict__ flag,
                           int* __restrict__ deg, long long E) {
    const int is32 = (*flag != 0);
    long long i = blockIdx.x * (long long)blockDim.x + threadIdx.x;
    const long long stride = (long long)gridDim.x * blockDim.x;
    for (; i < E; i += stride) {
        long long d = edge_at(ei, is32, E + i);
        atomicAdd(&deg[d], 1);
    }
}

// S[v] = sum over edges with src == v of dinv[dst]
__global__ void srcsum_kernel(const void* __restrict__ ei, const unsigned int* __restrict__ flag,
                              const int* __restrict__ deg, float* __restrict__ S, long long E) {
    const int is32 = (*flag != 0);
    long long i = blockIdx.x * (long long)blockDim.x + threadIdx.x;
    const long long stride = (long long)gridDim.x * blockDim.x;
    for (; i < E; i += stride) {
        long long s = edge_at(ei, is32, i);
        long long d = edge_at(ei, is32, E + i);
        float w = rsqrtf((float)(deg[d] + 1));
        atomicAdd(&S[s], w);
    }
}

// t[k] = sum_v coef[v] * x[v][k],  coef[v] = dinv[v]*S[v] + 1/deg[v]
__global__ void reduce_kernel(const float* __restrict__ x, const int* __restrict__ deg,
                              const float* __restrict__ S, float* __restrict__ t, long long n) {
    __shared__ float sm[FD];
    for (int f = threadIdx.x; f < FD; f += blockDim.x) sm[f] = 0.0f;
    __syncthreads();
    const long long total = n * (FD / 4);  // float4 count; 32 float4 per row
    long long i = blockIdx.x * (long long)blockDim.x + threadIdx.x;
    const long long stride = (long long)gridDim.x * blockDim.x;  // multiple of 32
    const int lane = threadIdx.x & 31;  // f4 column, constant per thread
    float4 acc = make_float4(0.f, 0.f, 0.f, 0.f);
    for (; i < total; i += stride) {
        long long v = i >> 5;  // node index
        float dg = (float)(deg[v] + 1);
        float dinv = rsqrtf(dg);
        float coef = dinv * S[v] + 1.0f / dg;
        float4 xv = ((const float4*)x)[i];
        acc.x += coef * xv.x;
        acc.y += coef * xv.y;
        acc.z += coef * xv.z;
        acc.w += coef * xv.w;
    }
    atomicAdd(&sm[lane * 4 + 0], acc.x);
    atomicAdd(&sm[lane * 4 + 1], acc.y);
    atomicAdd(&sm[lane * 4 + 2], acc.z);
    atomicAdd(&sm[lane * 4 + 3], acc.w);
    __syncthreads();
    for (int f = threadIdx.x; f < FD; f += blockDim.x)
        atomicAdd(&t[f], sm[f]);
}

// out[f] = sum_k W[f][k] * t[k] + n * bias[f]
__global__ void final_kernel(const float* __restrict__ W, const float* __restrict__ bias,
                             const float* __restrict__ t, float* __restrict__ out, float nn) {
    __shared__ float ts[FD];
    int f = threadIdx.x;
    if (f < FD) ts[f] = t[f];
    __syncthreads();
    if (f < FD) {
        float acc = 0.0f;
        #pragma unroll 16
        for (int k = 0; k < FD; ++k) acc += W[f * FD + k] * ts[k];
        out[f] = acc + nn * bias[f];
    }
}

extern "C" void kernel_launch(void* const* d_in, const int* in_sizes, int n_in,
                              void* d_out, int out_size, void* d_ws, size_t ws_size,
                              hipStream_t stream) {
    const float* x    = (const float*)d_in[0];
    const float* W    = (const float*)d_in[1];
    const float* bias = (const float*)d_in[2];
    const void*  ei   = d_in[3];
    const long long n = in_sizes[0] / FD;   // 100000
    const long long E = (long long)in_sizes[3] / 2;  // 1600000

    char* ws = (char*)d_ws;
    int*   deg  = (int*)ws;                         // n ints
    float* S    = (float*)(ws + n * 4);             // n floats
    float* t    = (float*)(ws + n * 8);             // FD floats
    unsigned int* flag = (unsigned int*)(ws + n * 8 + FD * 4);  // 1 uint

    size_t zero_bytes = (size_t)n * 8 + FD * 4 + 4;
    hipMemsetAsync(d_ws, 0, zero_bytes, stream);

    detect_kernel<<<1, 256, 0, stream>>>((const unsigned int*)ei, flag);

    const int blocks = 2048, threads = 256;
    deg_kernel<<<blocks, threads, 0, stream>>>(ei, flag, deg, E);
    srcsum_kernel<<<blocks, threads, 0, stream>>>(ei, flag, deg, S, E);
    reduce_kernel<<<blocks, threads, 0, stream>>>(x, deg, S, t, n);
    final_kernel<<<1, FD, 0, stream>>>(W, bias, t, (float*)d_out, (float)n);
}

// Round 2
// 212.194 us; speedup vs baseline: 1.0776x; 1.0776x over previous
//
#include <hip/hip_runtime.h>

#define FD 128
#define QSCALE 16777216.0f      // 2^24
#define QINV   5.9604644775390625e-8f

// Sample odd 32-bit words of edge_index. Values < 2^17, so int64 buffer =>
// every odd word (high half) is 0. Any nonzero odd word => int32.
__global__ void detect_kernel(const unsigned int* __restrict__ words,
                              unsigned int* __restrict__ flag_or) {
    unsigned int acc = 0;
    for (int i = threadIdx.x; i < 2048; i += blockDim.x)
        acc |= words[2 * i + 1];
    if (acc) atomicOr(flag_or, 1u);
}

// deg[v] = #edges with dst == v (self-loop +1 applied at read time)
__global__ void deg_kernel(const void* __restrict__ ei, const unsigned int* __restrict__ flag,
                           int* __restrict__ deg, long long E) {
    const bool is32 = (*flag != 0);
    const long long tid = blockIdx.x * (long long)blockDim.x + threadIdx.x;
    const long long stride4 = (long long)gridDim.x * blockDim.x * 4;
    const long long E4 = E & ~3LL;
    if (is32) {
        const int* pd = (const int*)ei + E;
        for (long long i = tid * 4; i < E4; i += stride4) {
            int4 d = *reinterpret_cast<const int4*>(pd + i);
            atomicAdd(&deg[d.x], 1);
            atomicAdd(&deg[d.y], 1);
            atomicAdd(&deg[d.z], 1);
            atomicAdd(&deg[d.w], 1);
        }
        if (tid < (E - E4)) atomicAdd(&deg[pd[E4 + tid]], 1);
    } else {
        const long long* pd = (const long long*)ei + E;
        for (long long i = tid * 4; i < E4; i += stride4) {
            longlong2 a = *reinterpret_cast<const longlong2*>(pd + i);
            longlong2 b = *reinterpret_cast<const longlong2*>(pd + i + 2);
            atomicAdd(&deg[(int)a.x], 1);
            atomicAdd(&deg[(int)a.y], 1);
            atomicAdd(&deg[(int)b.x], 1);
            atomicAdd(&deg[(int)b.y], 1);
        }
        if (tid < (E - E4)) atomicAdd(&deg[(int)pd[E4 + tid]], 1);
    }
}

__device__ __forceinline__ unsigned quant_w(int deg_plus1) {
    return (unsigned)(rsqrtf((float)deg_plus1) * QSCALE + 0.5f);
}

// Sq[v] = round(2^24 * sum over edges with src == v of dinv[dst])  (int atomics)
__global__ void srcsum_kernel(const void* __restrict__ ei, const unsigned int* __restrict__ flag,
                              const int* __restrict__ deg, unsigned int* __restrict__ Sq,
                              long long E) {
    const bool is32 = (*flag != 0);
    const long long tid = blockIdx.x * (long long)blockDim.x + threadIdx.x;
    const long long stride4 = (long long)gridDim.x * blockDim.x * 4;
    const long long E4 = E & ~3LL;
    if (is32) {
        const int* ps = (const int*)ei;
        const int* pd = ps + E;
        for (long long i = tid * 4; i < E4; i += stride4) {
            int4 s = *reinterpret_cast<const int4*>(ps + i);
            int4 d = *reinterpret_cast<const int4*>(pd + i);
            int g0 = deg[d.x] + 1, g1 = deg[d.y] + 1, g2 = deg[d.z] + 1, g3 = deg[d.w] + 1;
            atomicAdd(&Sq[s.x], quant_w(g0));
            atomicAdd(&Sq[s.y], quant_w(g1));
            atomicAdd(&Sq[s.z], quant_w(g2));
            atomicAdd(&Sq[s.w], quant_w(g3));
        }
        if (tid < (E - E4)) {
            long long i = E4 + tid;
            atomicAdd(&Sq[ps[i]], quant_w(deg[pd[i]] + 1));
        }
    } else {
        const long long* ps = (const long long*)ei;
        const long long* pd = ps + E;
        for (long long i = tid * 4; i < E4; i += stride4) {
            longlong2 s01 = *reinterpret_cast<const longlong2*>(ps + i);
            longlong2 s23 = *reinterpret_cast<const longlong2*>(ps + i + 2);
            longlong2 d01 = *reinterpret_cast<const longlong2*>(pd + i);
            longlong2 d23 = *reinterpret_cast<const longlong2*>(pd + i + 2);
            int g0 = deg[(int)d01.x] + 1, g1 = deg[(int)d01.y] + 1;
            int g2 = deg[(int)d23.x] + 1, g3 = deg[(int)d23.y] + 1;
            atomicAdd(&Sq[(int)s01.x], quant_w(g0));
            atomicAdd(&Sq[(int)s01.y], quant_w(g1));
            atomicAdd(&Sq[(int)s23.x], quant_w(g2));
            atomicAdd(&Sq[(int)s23.y], quant_w(g3));
        }
        if (tid < (E - E4)) {
            long long i = E4 + tid;
            atomicAdd(&Sq[(int)ps[i]], quant_w(deg[(int)pd[i]] + 1));
        }
    }
}

// t[k] = sum_v coef[v] * x[v][k],  coef[v] = dinv[v]*S[v] + 1/deg[v]
__global__ void reduce_kernel(const float* __restrict__ x, const int* __restrict__ deg,
                              const unsigned int* __restrict__ Sq, float* __restrict__ t,
                              long long n) {
    __shared__ float sm[FD];
    for (int f = threadIdx.x; f < FD; f += blockDim.x) sm[f] = 0.0f;
    __syncthreads();
    const long long total = n * (FD / 4);
    long long i = blockIdx.x * (long long)blockDim.x + threadIdx.x;
    const long long stride = (long long)gridDim.x * blockDim.x;
    const int lane = threadIdx.x & 31;
    float4 acc = make_float4(0.f, 0.f, 0.f, 0.f);
    for (; i < total; i += stride) {
        long long v = i >> 5;
        float dg = (float)(deg[v] + 1);
        float dinv = rsqrtf(dg);
        float coef = dinv * ((float)Sq[v] * QINV) + 1.0f / dg;
        float4 xv = ((const float4*)x)[i];
        acc.x += coef * xv.x;
        acc.y += coef * xv.y;
        acc.z += coef * xv.z;
        acc.w += coef * xv.w;
    }
    atomicAdd(&sm[lane * 4 + 0], acc.x);
    atomicAdd(&sm[lane * 4 + 1], acc.y);
    atomicAdd(&sm[lane * 4 + 2], acc.z);
    atomicAdd(&sm[lane * 4 + 3], acc.w);
    __syncthreads();
    for (int f = threadIdx.x; f < FD; f += blockDim.x)
        atomicAdd(&t[f], sm[f]);
}

// out[f] = sum_k W[f][k] * t[k] + n * bias[f]
__global__ void final_kernel(const float* __restrict__ W, const float* __restrict__ bias,
                             const float* __restrict__ t, float* __restrict__ out, float nn) {
    __shared__ float ts[FD];
    int f = threadIdx.x;
    if (f < FD) ts[f] = t[f];
    __syncthreads();
    if (f < FD) {
        float acc = 0.0f;
        #pragma unroll 16
        for (int k = 0; k < FD; ++k) acc += W[f * FD + k] * ts[k];
        out[f] = acc + nn * bias[f];
    }
}

extern "C" void kernel_launch(void* const* d_in, const int* in_sizes, int n_in,
                              void* d_out, int out_size, void* d_ws, size_t ws_size,
                              hipStream_t stream) {
    const float* x    = (const float*)d_in[0];
    const float* W    = (const float*)d_in[1];
    const float* bias = (const float*)d_in[2];
    const void*  ei   = d_in[3];
    const long long n = in_sizes[0] / FD;            // 100000
    const long long E = (long long)in_sizes[3] / 2;  // 1600000

    char* ws = (char*)d_ws;
    int*          deg  = (int*)ws;                               // n ints
    unsigned int* Sq   = (unsigned int*)(ws + n * 4);            // n uints
    float*        t    = (float*)(ws + n * 8);                   // FD floats
    unsigned int* flag = (unsigned int*)(ws + n * 8 + FD * 4);   // 1 uint

    size_t zero_bytes = (size_t)n * 8 + FD * 4 + 4;
    hipMemsetAsync(d_ws, 0, zero_bytes, stream);

    detect_kernel<<<1, 256, 0, stream>>>((const unsigned int*)ei, flag);

    // one edge-quad per thread: 1600 blocks * 256 threads * 4 = 1.64M >= E
    const int eblocks = 1600, threads = 256;
    deg_kernel<<<eblocks, threads, 0, stream>>>(ei, flag, deg, E);
    srcsum_kernel<<<eblocks, threads, 0, stream>>>(ei, flag, deg, Sq, E);
    reduce_kernel<<<2048, threads, 0, stream>>>(x, deg, Sq, t, n);
    final_kernel<<<1, FD, 0, stream>>>(W, bias, t, (float*)d_out, (float)n);
}

// Round 3
// 112.612 us; speedup vs baseline: 2.0305x; 1.8843x over previous
//
#include <hip/hip_runtime.h>

#define FD 128
#define CHUNK 16384           // nodes per LDS histogram chunk (64 KB)
#define LOG2CHUNK 14
#define NSLICE 32             // edge slices per chunk pass
#define QSCALE 16777216.0f    // 2^24
#define QINV   5.9604644775390625e-8f
#define RXB 2048              // reduce_x blocks

// ---------- dtype detect: odd 32-bit words all zero => int64 ----------
__global__ void detect_kernel(const unsigned int* __restrict__ words,
                              unsigned int* __restrict__ flag_or) {
    unsigned int acc = 0;
    for (int i = threadIdx.x; i < 2048; i += blockDim.x)
        acc |= words[2 * i + 1];
    if (acc) atomicOr(flag_or, 1u);
}

// ---------- int64 -> int32 conversion (no-op when already int32) ----------
__global__ void convert_kernel(const long long* __restrict__ e64,
                               const unsigned int* __restrict__ flag,
                               int* __restrict__ e32, long long total) {
    if (*flag) return;  // already int32, wave-uniform early-out
    const long long stride2 = (long long)gridDim.x * blockDim.x * 2;
    const long long tv = total & ~1LL;
    for (long long i = (blockIdx.x * (long long)blockDim.x + threadIdx.x) * 2;
         i < tv; i += stride2) {
        longlong2 v = *reinterpret_cast<const longlong2*>(e64 + i);
        *reinterpret_cast<int2*>(e32 + i) = make_int2((int)v.x, (int)v.y);
    }
    const long long stride1 = (long long)gridDim.x * blockDim.x;
    for (long long k = tv + blockIdx.x * (long long)blockDim.x + threadIdx.x;
         k < total; k += stride1)
        e32[k] = (int)e64[k];
}

__device__ __forceinline__ unsigned quant_w(int deg_plus1) {
    return (unsigned)(rsqrtf((float)deg_plus1) * QSCALE + 0.5f);
}

// ---------- phase 1: deg histogram, chunked LDS ----------
__global__ __launch_bounds__(256) void hist_deg_kernel(
        const void* __restrict__ ei, const int* __restrict__ e32,
        const unsigned int* __restrict__ flag, unsigned short* __restrict__ psD,
        long long E, long long SL, int nchunk) {
    __shared__ unsigned int hist[CHUNK];
    const bool is32 = (*flag != 0);
    const int c = blockIdx.x % nchunk;
    const int j = blockIdx.x / nchunk;
    const int lo = c * CHUNK;
    for (int i = threadIdx.x; i < CHUNK; i += 256) hist[i] = 0;
    __syncthreads();
    const int* pd = (is32 ? (const int*)ei : e32) + E;   // dst base
    const long long e0 = (long long)j * SL;
    const long long e1 = (e0 + SL < E) ? (e0 + SL) : E;
    const long long e1v = e0 + ((e1 - e0) & ~3LL);
    for (long long i = e0 + (long long)threadIdx.x * 4; i < e1v; i += 1024) {
        int4 d = *reinterpret_cast<const int4*>(pd + i);
        unsigned u0 = (unsigned)(d.x - lo), u1 = (unsigned)(d.y - lo);
        unsigned u2 = (unsigned)(d.z - lo), u3 = (unsigned)(d.w - lo);
        if (u0 < CHUNK) atomicAdd(&hist[u0], 1u);
        if (u1 < CHUNK) atomicAdd(&hist[u1], 1u);
        if (u2 < CHUNK) atomicAdd(&hist[u2], 1u);
        if (u3 < CHUNK) atomicAdd(&hist[u3], 1u);
    }
    {
        long long it = e1v + threadIdx.x;
        if (it < e1) {
            unsigned u = (unsigned)(pd[it] - lo);
            if (u < CHUNK) atomicAdd(&hist[u], 1u);
        }
    }
    __syncthreads();
    // flush as packed u16 (per-block per-slot count <= slice size < 65536)
    unsigned int* out = (unsigned int*)psD + (size_t)blockIdx.x * (CHUNK / 2);
    for (int w = threadIdx.x; w < CHUNK / 2; w += 256)
        out[w] = (hist[2 * w] & 0xffffu) | (hist[2 * w + 1] << 16);
}

// ---------- phase 1b: reduce deg partials ----------
__global__ void reduce_deg_kernel(const unsigned short* __restrict__ psD,
                                  int* __restrict__ deg, long long n, int nchunk) {
    const unsigned int* pw = (const unsigned int*)psD;
    const long long tw = blockIdx.x * (long long)blockDim.x + threadIdx.x;
    const long long nwords = (long long)nchunk * (CHUNK / 2);
    if (tw >= nwords) return;
    const int c = (int)(tw / (CHUNK / 2));
    const int wu = (int)(tw % (CHUNK / 2));
    const long long v0 = (long long)c * CHUNK + 2 * wu;
    if (v0 >= n) return;
    unsigned s0 = 0, s1 = 0;
    for (int j = 0; j < NSLICE; ++j) {
        unsigned w = pw[((long long)(j * nchunk + c)) * (CHUNK / 2) + wu];
        s0 += w & 0xffffu;
        s1 += w >> 16;
    }
    deg[v0] = (int)s0;
    if (v0 + 1 < n) deg[v0 + 1] = (int)s1;
}

// ---------- phase 2: per-edge quantized weight qw[e] = q(dinv[dst_e]) ----------
__global__ void qw_kernel(const void* __restrict__ ei, const int* __restrict__ e32,
                          const unsigned int* __restrict__ flag,
                          const int* __restrict__ deg, unsigned int* __restrict__ qw,
                          long long E) {
    const bool is32 = (*flag != 0);
    const int* pd = (is32 ? (const int*)ei : e32) + E;
    const long long stride4 = (long long)gridDim.x * blockDim.x * 4;
    const long long E4 = E & ~3LL;
    for (long long i = (blockIdx.x * (long long)blockDim.x + threadIdx.x) * 4;
         i < E4; i += stride4) {
        int4 d = *reinterpret_cast<const int4*>(pd + i);
        uint4 q;
        q.x = quant_w(deg[d.x] + 1);
        q.y = quant_w(deg[d.y] + 1);
        q.z = quant_w(deg[d.z] + 1);
        q.w = quant_w(deg[d.w] + 1);
        *reinterpret_cast<uint4*>(qw + i) = q;
    }
    const long long stride1 = (long long)gridDim.x * blockDim.x;
    for (long long k = E4 + blockIdx.x * (long long)blockDim.x + threadIdx.x;
         k < E; k += stride1)
        qw[k] = quant_w(deg[pd[k]] + 1);
}

// ---------- phase 3: S histogram (weighted by qw), chunked LDS ----------
__global__ __launch_bounds__(256) void hist_s_kernel(
        const void* __restrict__ ei, const int* __restrict__ e32,
        const unsigned int* __restrict__ flag, const unsigned int* __restrict__ qw,
        unsigned int* __restrict__ psS, long long E, long long SL, int nchunk) {
    __shared__ unsigned int hist[CHUNK];
    const bool is32 = (*flag != 0);
    const int c = blockIdx.x % nchunk;
    const int j = blockIdx.x / nchunk;
    const int lo = c * CHUNK;
    for (int i = threadIdx.x; i < CHUNK; i += 256) hist[i] = 0;
    __syncthreads();
    const int* ps = is32 ? (const int*)ei : e32;   // src base
    const long long e0 = (long long)j * SL;
    const long long e1 = (e0 + SL < E) ? (e0 + SL) : E;
    const long long e1v = e0 + ((e1 - e0) & ~3LL);
    for (long long i = e0 + (long long)threadIdx.x * 4; i < e1v; i += 1024) {
        int4 s = *reinterpret_cast<const int4*>(ps + i);
        uint4 q = *reinterpret_cast<const uint4*>(qw + i);
        unsigned u0 = (unsigned)(s.x - lo), u1 = (unsigned)(s.y - lo);
        unsigned u2 = (unsigned)(s.z - lo), u3 = (unsigned)(s.w - lo);
        if (u0 < CHUNK) atomicAdd(&hist[u0], q.x);
        if (u1 < CHUNK) atomicAdd(&hist[u1], q.y);
        if (u2 < CHUNK) atomicAdd(&hist[u2], q.z);
        if (u3 < CHUNK) atomicAdd(&hist[u3], q.w);
    }
    {
        long long it = e1v + threadIdx.x;
        if (it < e1) {
            unsigned u = (unsigned)(ps[it] - lo);
            if (u < CHUNK) atomicAdd(&hist[u], qw[it]);
        }
    }
    __syncthreads();
    unsigned int* out = psS + (size_t)blockIdx.x * CHUNK;
    for (int w = threadIdx.x; w < CHUNK; w += 256) out[w] = hist[w];
}

// ---------- phase 3b: reduce S partials -> coef[v] ----------
__global__ void reduce_coef_kernel(const unsigned int* __restrict__ psS,
                                   const int* __restrict__ deg,
                                   float* __restrict__ coef, long long n, int nchunk) {
    const long long v = blockIdx.x * (long long)blockDim.x + threadIdx.x;
    if (v >= n) return;
    const int c = (int)(v >> LOG2CHUNK);
    const int u = (int)(v & (CHUNK - 1));
    unsigned s = 0;
    for (int j = 0; j < NSLICE; ++j)
        s += psS[((long long)(j * nchunk + c)) * CHUNK + u];
    const float dg = (float)(deg[v] + 1);
    const float dinv = rsqrtf(dg);
    coef[v] = dinv * ((float)s * QINV) + 1.0f / dg;
}

// ---------- phase 4: t-partials: P[b][k] = block-partial of sum_v coef[v]*x[v][k] ----------
__global__ __launch_bounds__(256) void reduce_x_kernel(
        const float* __restrict__ x, const float* __restrict__ coef,
        float* __restrict__ P, long long n) {
    __shared__ float sm[FD];
    for (int f = threadIdx.x; f < FD; f += 256) sm[f] = 0.0f;
    __syncthreads();
    const long long total = n * (FD / 4);
    const long long stride = (long long)gridDim.x * blockDim.x;
    const int lane = threadIdx.x & 31;
    float4 acc = make_float4(0.f, 0.f, 0.f, 0.f);
    for (long long i = blockIdx.x * (long long)blockDim.x + threadIdx.x;
         i < total; i += stride) {
        long long v = i >> 5;
        float cf = coef[v];
        float4 xv = ((const float4*)x)[i];
        acc.x += cf * xv.x;
        acc.y += cf * xv.y;
        acc.z += cf * xv.z;
        acc.w += cf * xv.w;
    }
    atomicAdd(&sm[lane * 4 + 0], acc.x);
    atomicAdd(&sm[lane * 4 + 1], acc.y);
    atomicAdd(&sm[lane * 4 + 2], acc.z);
    atomicAdd(&sm[lane * 4 + 3], acc.w);
    __syncthreads();
    for (int f = threadIdx.x; f < FD; f += 256)
        P[(size_t)blockIdx.x * FD + f] = sm[f];
}

// ---------- phase 4b: column-sum the P partials -> t[f] ----------
__global__ void colsum_kernel(const float* __restrict__ P, int nb,
                              float* __restrict__ t) {
    // one block per feature f = blockIdx.x; 256 threads reduce nb rows
    __shared__ float sm[256];
    const int f = blockIdx.x;
    float s = 0.f;
    for (int j = threadIdx.x; j < nb; j += 256) s += P[(size_t)j * FD + f];
    sm[threadIdx.x] = s;
    __syncthreads();
    for (int w = 128; w > 0; w >>= 1) {
        if (threadIdx.x < w) sm[threadIdx.x] += sm[threadIdx.x + w];
        __syncthreads();
    }
    if (threadIdx.x == 0) t[f] = sm[0];
}

// ---------- final: out[f] = sum_k W[f][k]*t[k] + n*bias[f] ----------
__global__ void final_kernel(const float* __restrict__ W, const float* __restrict__ bias,
                             const float* __restrict__ t, float* __restrict__ out, float nn) {
    __shared__ float ts[FD];
    int f = threadIdx.x;
    if (f < FD) ts[f] = t[f];
    __syncthreads();
    if (f < FD) {
        float acc = 0.0f;
        #pragma unroll 16
        for (int k = 0; k < FD; ++k) acc += W[f * FD + k] * ts[k];
        out[f] = acc + nn * bias[f];
    }
}

// ================= fallback path (global atomics, proven in R2) =================
__device__ __forceinline__ long long edge_at(const void* ei, int is32, long long idx) {
    return is32 ? (long long)((const int*)ei)[idx] : ((const long long*)ei)[idx];
}

__global__ void deg_fb_kernel(const void* __restrict__ ei, const unsigned int* __restrict__ flag,
                              int* __restrict__ deg, long long E) {
    const int is32 = (*flag != 0);
    long long i = blockIdx.x * (long long)blockDim.x + threadIdx.x;
    const long long stride = (long long)gridDim.x * blockDim.x;
    for (; i < E; i += stride) {
        long long d = edge_at(ei, is32, E + i);
        atomicAdd(&deg[d], 1);
    }
}

__global__ void srcsum_fb_kernel(const void* __restrict__ ei, const unsigned int* __restrict__ flag,
                                 const int* __restrict__ deg, unsigned int* __restrict__ Sq,
                                 long long E) {
    const int is32 = (*flag != 0);
    long long i = blockIdx.x * (long long)blockDim.x + threadIdx.x;
    const long long stride = (long long)gridDim.x * blockDim.x;
    for (; i < E; i += stride) {
        long long s = edge_at(ei, is32, i);
        long long d = edge_at(ei, is32, E + i);
        atomicAdd(&Sq[s], quant_w(deg[d] + 1));
    }
}

__global__ void coef_fb_kernel(const unsigned int* __restrict__ Sq, const int* __restrict__ deg,
                               float* __restrict__ coef, long long n) {
    const long long v = blockIdx.x * (long long)blockDim.x + threadIdx.x;
    if (v >= n) return;
    unsigned s = Sq[v];
    const float dg = (float)(deg[v] + 1);
    const float dinv = rsqrtf(dg);
    coef[v] = dinv * ((float)s * QINV) + 1.0f / dg;   // in-place over Sq is safe (own slot)
}

__global__ void reduce_x_atomic_kernel(const float* __restrict__ x, const float* __restrict__ coef,
                                       float* __restrict__ t, long long n) {
    __shared__ float sm[FD];
    for (int f = threadIdx.x; f < FD; f += 256) sm[f] = 0.0f;
    __syncthreads();
    const long long total = n * (FD / 4);
    const long long stride = (long long)gridDim.x * blockDim.x;
    const int lane = threadIdx.x & 31;
    float4 acc = make_float4(0.f, 0.f, 0.f, 0.f);
    for (long long i = blockIdx.x * (long long)blockDim.x + threadIdx.x;
         i < total; i += stride) {
        long long v = i >> 5;
        float cf = coef[v];
        float4 xv = ((const float4*)x)[i];
        acc.x += cf * xv.x;
        acc.y += cf * xv.y;
        acc.z += cf * xv.z;
        acc.w += cf * xv.w;
    }
    atomicAdd(&sm[lane * 4 + 0], acc.x);
    atomicAdd(&sm[lane * 4 + 1], acc.y);
    atomicAdd(&sm[lane * 4 + 2], acc.z);
    atomicAdd(&sm[lane * 4 + 3], acc.w);
    __syncthreads();
    for (int f = threadIdx.x; f < FD; f += 256)
        atomicAdd(&t[f], sm[f]);
}

// ==============================================================================
extern "C" void kernel_launch(void* const* d_in, const int* in_sizes, int n_in,
                              void* d_out, int out_size, void* d_ws, size_t ws_size,
                              hipStream_t stream) {
    const float* x    = (const float*)d_in[0];
    const float* W    = (const float*)d_in[1];
    const float* bias = (const float*)d_in[2];
    const void*  ei   = d_in[3];
    const long long n = in_sizes[0] / FD;            // 100000
    const long long E = (long long)in_sizes[3] / 2;  // 1600000
    const int nchunk  = (int)((n + CHUNK - 1) / CHUNK);
    const long long SL = ((E + NSLICE - 1) / NSLICE + 3) & ~3LL;

    char* ws = (char*)d_ws;
    float*        t    = (float*)ws;                        // 512 B
    unsigned int* flag = (unsigned int*)(ws + 512);         // 4 B (pad to 1024)
    int*          deg  = (int*)(ws + 1024);                 // n*4
    char*         cs   = ws + 1024 + n * 4;                 // n*4: coef (main) / Sq->coef (fb)
    float*        coef = (float*)cs;
    char*         extra = cs + n * 4;
    int*          e32  = (int*)extra;                       // 2E*4
    unsigned int* qw   = (unsigned int*)(extra + 2 * E * 4);            // E*4
    unsigned int* psS  = (unsigned int*)(extra + 2 * E * 4 + E * 4);    // nchunk*NSLICE*CHUNK*4
    unsigned short* psD = (unsigned short*)psS;             // overlays psS (phase-disjoint)
    float*        P    = (float*)psS;                       // overlays psS (phase-disjoint)

    const size_t need_main = 1024 + (size_t)n * 8 + (size_t)E * 12 +
                             (size_t)nchunk * NSLICE * CHUNK * 4;

    if (ws_size >= need_main) {
        hipMemsetAsync(ws, 0, 1024, stream);  // t + flag
        detect_kernel<<<1, 256, 0, stream>>>((const unsigned int*)ei, flag);
        convert_kernel<<<1024, 256, 0, stream>>>((const long long*)ei, flag, e32, 2 * E);
        const int hblocks = nchunk * NSLICE;  // 224
        hist_deg_kernel<<<hblocks, 256, 0, stream>>>(ei, e32, flag, psD, E, SL, nchunk);
        {
            int rb = (int)(((long long)nchunk * (CHUNK / 2) + 255) / 256);
            reduce_deg_kernel<<<rb, 256, 0, stream>>>(psD, deg, n, nchunk);
        }
        {
            int qb = (int)((E / 4 + 255) / 256);
            qw_kernel<<<qb, 256, 0, stream>>>(ei, e32, flag, deg, qw, E);
        }
        hist_s_kernel<<<hblocks, 256, 0, stream>>>(ei, e32, flag, qw, psS, E, SL, nchunk);
        {
            int cb = (int)((n + 255) / 256);
            reduce_coef_kernel<<<cb, 256, 0, stream>>>(psS, deg, coef, n, nchunk);
        }
        reduce_x_kernel<<<RXB, 256, 0, stream>>>(x, coef, P, n);
        colsum_kernel<<<FD, 256, 0, stream>>>(P, RXB, t);
        final_kernel<<<1, FD, 0, stream>>>(W, bias, t, (float*)d_out, (float)n);
    } else {
        // R2-proven atomic fallback
        hipMemsetAsync(ws, 0, 1024 + (size_t)n * 8, stream);
        detect_kernel<<<1, 256, 0, stream>>>((const unsigned int*)ei, flag);
        deg_fb_kernel<<<1600, 256, 0, stream>>>(ei, flag, deg, E);
        srcsum_fb_kernel<<<1600, 256, 0, stream>>>(ei, flag, deg, (unsigned int*)cs, E);
        {
            int cb = (int)((n + 255) / 256);
            coef_fb_kernel<<<cb, 256, 0, stream>>>((unsigned int*)cs, deg, coef, n);
        }
        reduce_x_atomic_kernel<<<RXB, 256, 0, stream>>>(x, coef, t, n);
        final_kernel<<<1, FD, 0, stream>>>(W, bias, t, (float*)d_out, (float)n);
    }
}